// Round 8
// baseline (1399.423 us; speedup 1.0000x reference)
//
#include <hip/hip_runtime.h>
#include <stdint.h>

// Problem constants (fixed by the reference)
#define B_ 4
#define T_ 512
#define L_ 15
#define D_ 2048
#define H_ 1024
#define TL_ (T_*L_)            // 7680
#define M_ (B_*TL_)            // 30720
#define K_SPANS 205
#define NSORT 8192
#define NPART 16               // score partials = 16 x 64-col slices

// d_out float offsets (outputs concatenated flat in return order)
#define OFF_PRUNE 0                                   // [B,T,L,1]  30720
#define OFF_TOP   (OFF_PRUNE + M_)                    // [B,K]      820
#define OFF_FVECS (OFF_TOP + B_*K_SPANS)              // [B,K,D]    1679360
#define OFF_FSC   (OFF_FVECS + B_*K_SPANS*D_)         // [B,K,1]
#define OFF_FBEG  (OFF_FSC + B_*K_SPANS)
#define OFF_FEND  (OFF_FBEG + B_*K_SPANS)
#define OFF_SL    (OFF_FEND + B_*K_SPANS)
#define OFF_SQ    (OFF_SL + B_)
#define OFF_TRI   (OFF_SQ + B_*K_SPANS*K_SPANS)

typedef __attribute__((ext_vector_type(8))) short s16x8;   // 8 bf16 = 4 VGPRs
typedef __attribute__((ext_vector_type(4))) float f32x4;   // MFMA C/D frag

// ---- exact fp32 -> bf16 split helpers (RNE) --------------------------------
__device__ __forceinline__ ushort bf16rne(float f) {
    uint u = __float_as_uint(f);
    return (ushort)((u + 0x7fffu + ((u >> 16) & 1u)) >> 16);
}
__device__ __forceinline__ float bfval(ushort h) {
    return __uint_as_float(((uint)h) << 16);
}
// 3-term split (fallback path only)
__device__ __forceinline__ void split1(float x, ushort& h0, ushort& h1, ushort& h2) {
    h0 = bf16rne(x);            float f0 = bfval(h0);
    float r = x - f0;           h1 = bf16rne(r);
    float r2 = r - bfval(h1);   h2 = bf16rne(r2);
}
__device__ __forceinline__ void split4(float4 v, uint2& q0, uint2& q1, uint2& q2) {
    ushort a0[4], a1[4], a2[4];
    float x[4] = {v.x, v.y, v.z, v.w};
    #pragma unroll
    for (int j = 0; j < 4; ++j) split1(x[j], a0[j], a1[j], a2[j]);
    q0 = make_uint2((uint)a0[0] | ((uint)a0[1] << 16), (uint)a0[2] | ((uint)a0[3] << 16));
    q1 = make_uint2((uint)a1[0] | ((uint)a1[1] << 16), (uint)a1[2] | ((uint)a1[3] << 16));
    q2 = make_uint2((uint)a2[0] | ((uint)a2[1] << 16), (uint)a2[2] | ((uint)a2[3] << 16));
}
// 2-term split (fast path): x ~= bf(h0) + bf(h1), residual <= 2^-18 |x|.
// Validated R4: absmax 0.00098 (same as 3-term), dur -38%.
__device__ __forceinline__ void split2(float x, ushort& h0, ushort& h1) {
    h0 = bf16rne(x);            float f0 = bfval(h0);
    h1 = bf16rne(x - f0);
}
__device__ __forceinline__ void split4_2(float4 v, uint2& q0, uint2& q1) {
    ushort a0[4], a1[4];
    float x[4] = {v.x, v.y, v.z, v.w};
    #pragma unroll
    for (int j = 0; j < 4; ++j) split2(x[j], a0[j], a1[j]);
    q0 = make_uint2((uint)a0[0] | ((uint)a0[1] << 16), (uint)a0[2] | ((uint)a0[3] << 16));
    q1 = make_uint2((uint)a1[0] | ((uint)a1[1] << 16), (uint)a1[2] | ((uint)a1[3] << 16));
}

__device__ __forceinline__ f32x4 mfma16(s16x8 a, s16x8 b, f32x4 c) {
    return __builtin_amdgcn_mfma_f32_16x16x32_bf16(a, b, c, 0, 0, 0);
}

// ===========================================================================
// FAST PATH — 2-panel split-bf16 (R4/R5-proven core).
// Panels are stored in MFMA fragment-tile layout:
//   tile = (row16_idx * K32 + g), 1024 B per tile,
//   lane l (l=0..63) owns 8 bf16 at tile*1024 + l*16:
//     A-panel: A[row16*16 + (l&15)][g*32 + (l>>4)*8 + j]
//     B-panel: W[g*32 + (l>>4)*8 + j][n16*16 + (l&15)]
// so a wave loads a whole fragment with ONE coalesced dwordx4 at voffs l*16.
// ===========================================================================

// A [ROWS, K32*32] fp32 row-major -> 2 split panels in frag-tile layout.
template<int K32>
__global__ __launch_bounds__(256) void split_a_panel(
    const float* __restrict__ A, ushort* __restrict__ P0,
    ushort* __restrict__ P1)
{
    const int l    = threadIdx.x & 63;
    const int w    = threadIdx.x >> 6;
    const int tile = blockIdx.x * 4 + w;
    const int r16  = tile / K32;
    const int g    = tile % K32;
    const int row  = r16 * 16 + (l & 15);
    const int k0   = g * 32 + (l >> 4) * 8;
    const float* src = A + (size_t)row * (K32 * 32) + k0;
    float4 v0 = *(const float4*)src;
    float4 v1 = *(const float4*)(src + 4);
    uint2 a0, a1, b0, b1;
    split4_2(v0, a0, a1);
    split4_2(v1, b0, b1);
    const size_t off = ((size_t)tile * 64 + l) * 8;
    *(uint4*)(P0 + off) = make_uint4(a0.x, a0.y, b0.x, b0.y);
    *(uint4*)(P1 + off) = make_uint4(a1.x, a1.y, b1.x, b1.y);
}

// W [K32*32, 1024] fp32 -> 2 split panels in frag-tile layout (B-operand).
template<int K32>
__global__ __launch_bounds__(256) void split_w_frag(
    const float* __restrict__ W, ushort* __restrict__ P0,
    ushort* __restrict__ P1)
{
    const int idx  = blockIdx.x * 256 + threadIdx.x;
    const int l    = idx & 63;
    const int tile = idx >> 6;
    const int n16  = tile / K32;
    const int g    = tile % K32;
    const int n    = n16 * 16 + (l & 15);
    const int kb   = g * 32 + (l >> 4) * 8;
    ushort h0[8], h1[8];
    #pragma unroll
    for (int j = 0; j < 8; ++j) {
        float wv = W[(size_t)(kb + j) * 1024 + n];
        split2(wv, h0[j], h1[j]);
    }
    const size_t off = (size_t)idx * 8;
    *(uint4*)(P0 + off) = *(uint4*)h0;
    *(uint4*)(P1 + off) = *(uint4*)h1;
}

// LDS-free split-bf16 MFMA GEMM, fragments straight from panels.
// R7 geometry: block = 128m x 128n, 4 waves as 2x2 of 64x64 (was 256m x 64n).
// Rationale: FETCH ~ 4.8x A-panel unique bytes, insensitive to placement
// (R1/R2) and phase; the untested knob is SHARER COUNT — every A-byte was
// instruction-read by 16 n-blocks (3.8 GB instr-reads, 27% miss -> 1.05 GB
// HBM). 128x128 halves A instr-reads (8 sharers); B instr-reads double but
// B's 8.4 MB working set is unchanged and already fully cache-served.
// g-loop body/loads/MFMA structure are IDENTICAL to the proven R5 kernel
// (R6 showed thinning the MFMA burst starves the load pipeline: -25% MFMA
// => BW 3.03->2.46 TB/s, dur +8% — full 4-MFMA scheme restored).
template<int K32, bool FUSE>
__global__ __launch_bounds__(256, 2) void gemm_frag(
    const ushort* __restrict__ Ap0, const ushort* __restrict__ Ap1,
    const ushort* __restrict__ Bp0, const ushort* __restrict__ Bp1,
    const float* __restrict__ bias, const float* __restrict__ W3,
    float* __restrict__ outF, ushort* __restrict__ outP0,
    ushort* __restrict__ outP1)
{
    const int tid = threadIdx.x;
    const int l   = tid & 63;
    const int w   = tid >> 6;
    const int wr  = w >> 1;                    // wave row (0..1)
    const int wc  = w & 1;                     // wave col (0..1)
    const int lr  = l & 15;
    const int lq  = l >> 4;
    const int mb  = blockIdx.y * 8 + wr * 4;   // base m16-tile (4 per wave)
    const int nb  = blockIdx.x * 8 + wc * 4;   // base n16-tile (4 per wave)
    const int n0  = nb * 16;                   // base n column of this wave

    size_t aoff[4], boff[4];
    #pragma unroll
    for (int t = 0; t < 4; ++t) {
        aoff[t] = ((size_t)(mb + t) * K32 * 64 + l) * 8;
        boff[t] = ((size_t)(nb + t) * K32 * 64 + l) * 8;
    }

    f32x4 acc[4][4] = {};

    const int rot = ((w + blockIdx.x + blockIdx.y) & 3) * (K32 / 4);

    for (int gi = 0; gi < K32; ++gi) {
        int g = gi + rot;
        g -= (g >= K32) ? K32 : 0;
        s16x8 A0[4], A1[4], B0[4], B1[4];
        const size_t gofs = (size_t)g * 512;
        #pragma unroll
        for (int t = 0; t < 4; ++t) {
            const size_t ao = aoff[t] + gofs;
            const size_t bo = boff[t] + gofs;
            A0[t] = *(const s16x8*)(Ap0 + ao);
            A1[t] = *(const s16x8*)(Ap1 + ao);
            B0[t] = *(const s16x8*)(Bp0 + bo);
            B1[t] = *(const s16x8*)(Bp1 + bo);
        }
        #pragma unroll
        for (int mt = 0; mt < 4; ++mt)
            #pragma unroll
            for (int nt = 0; nt < 4; ++nt) {
                f32x4 c = acc[mt][nt];
                c = mfma16(A0[mt], B0[nt], c);
                c = mfma16(A0[mt], B1[nt], c);
                c = mfma16(A1[mt], B0[nt], c);
                c = mfma16(A1[mt], B1[nt], c);
                acc[mt][nt] = c;
            }
    }

    // C/D layout: col = lane&15, row = (lane>>4)*4 + reg  [m89-verified]
    float bv[4];
    #pragma unroll
    for (int nt = 0; nt < 4; ++nt) bv[nt] = bias[n0 + nt * 16 + lr];

    if (!FUSE) {
        // Fused relu + 2-term split + h1-panel write (R5-proven).
        // Wave covers cols [bx*128 + wc*64, +64) = GEMM2 k-groups
        // (bx*4 + wc*2) and (bx*4 + wc*2 + 1).
        __shared__ float sT[4][16][65];
        const int KH32 = 32;                   // h1 panels: K32 = H/32
        #pragma unroll
        for (int mt = 0; mt < 4; ++mt) {
            #pragma unroll
            for (int nt = 0; nt < 4; ++nt)
                #pragma unroll
                for (int r = 0; r < 4; ++r)
                    sT[w][lq * 4 + r][nt * 16 + lr] =
                        fmaxf(acc[mt][nt][r] + bv[nt], 0.f);
            __syncthreads();
            const int r16 = mb + mt;
            #pragma unroll
            for (int gg = 0; gg < 2; ++gg) {
                ushort h0[8], h1v[8];
                #pragma unroll
                for (int jj = 0; jj < 8; ++jj) {
                    float v = sT[w][lr][gg * 32 + lq * 8 + jj];
                    split2(v, h0[jj], h1v[jj]);
                }
                const size_t off =
                    ((size_t)(r16 * KH32 + blockIdx.x * 4 + wc * 2 + gg) * 64 + l) * 8;
                *(uint4*)(outP0 + off) = *(uint4*)h0;
                *(uint4*)(outP1 + off) = *(uint4*)h1v;
            }
            __syncthreads();
        }
    } else {
        // partial slot = bx*2 + wc (16 slots of 64 cols; topk sums all 16).
        float wv[4];
        #pragma unroll
        for (int nt = 0; nt < 4; ++nt) wv[nt] = W3[n0 + nt * 16 + lr];
        #pragma unroll
        for (int mt = 0; mt < 4; ++mt)
            #pragma unroll
            for (int r = 0; r < 4; ++r) {
                float v = 0.f;
                #pragma unroll
                for (int nt = 0; nt < 4; ++nt)
                    v += fmaxf(acc[mt][nt][r] + bv[nt], 0.f) * wv[nt];
                v += __shfl_xor(v, 1);
                v += __shfl_xor(v, 2);
                v += __shfl_xor(v, 4);
                v += __shfl_xor(v, 8);
                if (lr == 0)
                    outF[(size_t)(blockIdx.x * 2 + wc) * M_ +
                         (mb + mt) * 16 + lq * 4 + r] = v;
            }
    }
}

// ===========================================================================
// FALLBACK PATH (R2, ~147 MB ws) — unchanged, proven correct.
// ===========================================================================
__global__ void split_w_panel(const float* __restrict__ W, ushort* __restrict__ P0,
                              ushort* __restrict__ P1, ushort* __restrict__ P2, int K8)
{
    const int idx = blockIdx.x * 256 + threadIdx.x;
    if (idx >= K8 * 1024) return;
    const int k8 = idx >> 10;
    const int n  = idx & 1023;
    ushort h0[8], h1[8], h2[8];
    #pragma unroll
    for (int j = 0; j < 8; ++j) {
        float w = W[(size_t)(k8 * 8 + j) * 1024 + n];
        split1(w, h0[j], h1[j], h2[j]);
    }
    *(uint4*)(P0 + (size_t)idx * 8) = *(uint4*)h0;
    *(uint4*)(P1 + (size_t)idx * 8) = *(uint4*)h1;
    *(uint4*)(P2 + (size_t)idx * 8) = *(uint4*)h2;
}

template<int KDIM, bool FUSE>
__global__ __launch_bounds__(256, 2) void gemm_split(
    const float* __restrict__ A,
    const ushort* __restrict__ P0, const ushort* __restrict__ P1,
    const ushort* __restrict__ P2,
    const float* __restrict__ bias, const float* __restrict__ W3,
    float* __restrict__ out)
{
    __shared__ ushort aLds[3][4 * 257 * 8];
    __shared__ ushort bLds[3][4 * 65 * 8];

    const int tid   = threadIdx.x;
    const int lane  = tid & 63;
    const int lr    = lane & 15;
    const int lq    = lane >> 4;
    const int waveM = (tid >> 6) * 64;
    const int m0    = blockIdx.y * 256;
    const int n0    = blockIdx.x * 64;

    const int bq = tid >> 6;
    const int bn = tid & 63;
    const int ar = tid >> 3;
    const int ac4 = tid & 7;

    f32x4 acc[4][4] = {};

    for (int kt = 0; kt < KDIM / 32; ++kt) {
        const int k80 = kt * 4;
        const size_t bchunk = ((size_t)(k80 + bq) * 1024 + n0 + bn) * 8;
        uint4 bf0 = *(const uint4*)(P0 + bchunk);
        uint4 bf1 = *(const uint4*)(P1 + bchunk);
        uint4 bf2 = *(const uint4*)(P2 + bchunk);
        float4 av[8];
        #pragma unroll
        for (int sw = 0; sw < 8; ++sw) {
            const int row = sw * 32 + ar;
            av[sw] = *(const float4*)(A + (size_t)(m0 + row) * KDIM + kt * 32 + ac4 * 4);
        }
        __syncthreads();
        *(uint4*)&bLds[0][(bq * 65 + bn) * 8] = bf0;
        *(uint4*)&bLds[1][(bq * 65 + bn) * 8] = bf1;
        *(uint4*)&bLds[2][(bq * 65 + bn) * 8] = bf2;
        #pragma unroll
        for (int sw = 0; sw < 8; ++sw) {
            const int row = sw * 32 + ar;
            uint2 q0, q1, q2;
            split4(av[sw], q0, q1, q2);
            const int off = ((ac4 >> 1) * 257 + row) * 8 + (ac4 & 1) * 4;
            *(uint2*)&aLds[0][off] = q0;
            *(uint2*)&aLds[1][off] = q1;
            *(uint2*)&aLds[2][off] = q2;
        }
        __syncthreads();

        s16x8 B0[4], B1[4], B2[4];
        #pragma unroll
        for (int nt = 0; nt < 4; ++nt) {
            const int boff = (lq * 65 + nt * 16 + lr) * 8;
            B0[nt] = *(const s16x8*)&bLds[0][boff];
            B1[nt] = *(const s16x8*)&bLds[1][boff];
            B2[nt] = *(const s16x8*)&bLds[2][boff];
        }
        #pragma unroll
        for (int mt = 0; mt < 4; ++mt) {
            const int aoff = (lq * 257 + waveM + mt * 16 + lr) * 8;
            s16x8 A0 = *(const s16x8*)&aLds[0][aoff];
            s16x8 A1 = *(const s16x8*)&aLds[1][aoff];
            s16x8 A2 = *(const s16x8*)&aLds[2][aoff];
            #pragma unroll
            for (int nt = 0; nt < 4; ++nt) {
                f32x4 c = acc[mt][nt];
                c = mfma16(A0, B0[nt], c);
                c = mfma16(A0, B1[nt], c);
                c = mfma16(A1, B0[nt], c);
                c = mfma16(A1, B1[nt], c);
                c = mfma16(A0, B2[nt], c);
                c = mfma16(A2, B0[nt], c);
                acc[mt][nt] = c;
            }
        }
    }

    float bv[4];
    #pragma unroll
    for (int nt = 0; nt < 4; ++nt) bv[nt] = bias[n0 + nt * 16 + lr];

    if (!FUSE) {
        #pragma unroll
        for (int mt = 0; mt < 4; ++mt)
            #pragma unroll
            for (int nt = 0; nt < 4; ++nt)
                #pragma unroll
                for (int r = 0; r < 4; ++r) {
                    const int row = m0 + waveM + mt * 16 + lq * 4 + r;
                    out[(size_t)row * 1024 + n0 + nt * 16 + lr] =
                        fmaxf(acc[mt][nt][r] + bv[nt], 0.f);
                }
    } else {
        float wv[4];
        #pragma unroll
        for (int nt = 0; nt < 4; ++nt) wv[nt] = W3[n0 + nt * 16 + lr];
        #pragma unroll
        for (int mt = 0; mt < 4; ++mt)
            #pragma unroll
            for (int r = 0; r < 4; ++r) {
                float v = 0.f;
                #pragma unroll
                for (int nt = 0; nt < 4; ++nt)
                    v += fmaxf(acc[mt][nt][r] + bv[nt], 0.f) * wv[nt];
                v += __shfl_xor(v, 1);
                v += __shfl_xor(v, 2);
                v += __shfl_xor(v, 4);
                v += __shfl_xor(v, 8);
                if (lr == 0)
                    out[(size_t)blockIdx.x * M_ + m0 + waveM + mt * 16 + lq * 4 + r] = v;
            }
    }
}

// ===========================================================================
// Top-K / gather / masks (shared by both paths)
// ===========================================================================
__device__ __forceinline__ uint64_t score_key(float s, int idx) {
    unsigned u = __float_as_uint(s);
    u = (u & 0x80000000u) ? ~u : (u | 0x80000000u);
    return ((uint64_t)u << 32) | (uint64_t)(0xFFFFFFFFu - (unsigned)idx);
}

__device__ __forceinline__ float compute_score(
    const float* __restrict__ partial, const float* __restrict__ mask,
    float b3v, int b, int i)
{
    const int m = b * TL_ + i;
    float s = b3v;
    #pragma unroll
    for (int cb = 0; cb < NPART; ++cb) s += partial[(size_t)cb * M_ + m];
    s -= (1.0f - mask[m]) * 10000.0f;
    return s;
}

__global__ __launch_bounds__(1024) void topk_kernel(
    const float* __restrict__ partial, const float* __restrict__ span_mask,
    const int* __restrict__ span_begin, const int* __restrict__ span_end,
    const int* __restrict__ seq_len, const float* __restrict__ b3,
    float* __restrict__ out, int* __restrict__ topk_ws)
{
    __shared__ uint64_t keys[NSORT];
    const int tid = threadIdx.x;
    const int b   = blockIdx.x;
    const float b3v = b3[0];

    for (int i = tid; i < NSORT; i += 1024) {
        if (i < TL_) {
            float s = compute_score(partial, span_mask, b3v, b, i);
            out[OFF_PRUNE + b * TL_ + i] = s;
            keys[i] = score_key(s, i);
        } else {
            keys[i] = 0ull;
        }
    }
    __syncthreads();

    for (unsigned kk = 2; kk <= NSORT; kk <<= 1) {
        for (unsigned j = kk >> 1; j > 0; j >>= 1) {
            for (unsigned i = (unsigned)tid; i < NSORT; i += 1024) {
                unsigned ixj = i ^ j;
                if (ixj > i) {
                    uint64_t x = keys[i], y = keys[ixj];
                    bool desc = ((i & kk) == 0);
                    if (desc ? (x < y) : (x > y)) { keys[i] = y; keys[ixj] = x; }
                }
            }
            __syncthreads();
        }
    }

    const uint64_t cutoff = keys[K_SPANS - 1];
    __syncthreads();

    unsigned* sScan = (unsigned*)keys;
    unsigned base = 0;
    const unsigned lane = tid & 63;
    const unsigned wv   = tid >> 6;
    for (int c = 0; c < TL_; c += 1024) {
        const int i = c + tid;
        bool flag = false; float s = 0.f;
        if (i < TL_) {
            // Read back the score stored in pass 1 (bitwise identical).
            s = out[OFF_PRUNE + b * TL_ + i];
            flag = (score_key(s, i) >= cutoff);
        }
        uint64_t bal = __ballot(flag);
        unsigned pre = (unsigned)__popcll(bal & ((1ull << lane) - 1ull));
        if (lane == 0) sScan[wv] = (unsigned)__popcll(bal);
        __syncthreads();
        unsigned woff = 0, tot = 0;
        for (int w = 0; w < 16; ++w) {
            unsigned v = sScan[w];
            if (w < (int)wv) woff += v;
            tot += v;
        }
        if (flag) {
            const int g = b * K_SPANS + (int)(base + woff + pre);
            topk_ws[g]        = i;
            out[OFF_TOP + g]  = (float)i;
            out[OFF_FSC + g]  = s;
            out[OFF_FBEG + g] = (float)span_begin[b * TL_ + i];
            out[OFF_FEND + g] = (float)span_end[b * TL_ + i];
        }
        base += tot;
        __syncthreads();
    }

    if (tid == 0)
        out[OFF_SL + b] = ceilf(0.4f * (float)seq_len[b]);
}

__global__ void gather_vecs(const float* __restrict__ span_vecs,
                            const int* __restrict__ topk_ws,
                            float* __restrict__ out)
{
    const int bk  = blockIdx.x;
    const int b   = bk / K_SPANS;
    const int row = topk_ws[bk];
    const float4* src = (const float4*)(span_vecs + ((size_t)b * TL_ + row) * D_);
    float4* dst = (float4*)(out + OFF_FVECS + (size_t)bk * D_);
    for (int j = threadIdx.x; j < D_ / 4; j += blockDim.x) dst[j] = src[j];
}

__global__ void masks_kernel(const int* __restrict__ seq_len,
                             float* __restrict__ out)
{
    const int idx = blockIdx.x * blockDim.x + threadIdx.x;
    if (idx >= B_ * K_SPANS * K_SPANS) return;
    const int b = idx / (K_SPANS * K_SPANS);
    const int r = idx - b * K_SPANS * K_SPANS;
    const int i = r / K_SPANS;
    const int j = r - i * K_SPANS;
    const int sl = (int)ceilf(0.4f * (float)seq_len[b]);
    const float v = (i < sl && j < sl) ? 1.0f : 0.0f;
    out[OFF_SQ + idx]  = v;
    out[OFF_TRI + idx] = (j <= i) ? v : 0.0f;
}

// ===========================================================================
extern "C" void kernel_launch(void* const* d_in, const int* in_sizes, int n_in,
                              void* d_out, int out_size, void* d_ws, size_t ws_size,
                              hipStream_t stream)
{
    const float* span_vecs  = (const float*)d_in[0];
    const float* span_mask  = (const float*)d_in[1];
    const int*   span_begin = (const int*)  d_in[2];
    const int*   span_end   = (const int*)  d_in[3];
    const int*   seq_len    = (const int*)  d_in[4];
    const float* W1 = (const float*)d_in[5];
    const float* b1 = (const float*)d_in[6];
    const float* W2 = (const float*)d_in[7];
    const float* b2 = (const float*)d_in[8];
    const float* W3 = (const float*)d_in[9];
    const float* b3 = (const float*)d_in[10];
    float* out = (float*)d_out;

    const size_t A1CH = (size_t)M_ * D_;        // ushorts per A1 panel chunk
    const size_t H1CH = (size_t)M_ * H_;        // ushorts per h1 panel chunk
    const size_t W1CH = (size_t)D_ * H_;        // ushorts per W1 panel chunk
    const size_t W2CH = (size_t)H_ * H_;        // ushorts per W2 panel chunk
    const size_t FAST_NEED =
        2 * A1CH * 2 + 2 * H1CH * 2 +
        2 * W1CH * 2 + 2 * W2CH * 2 + (size_t)NPART * M_ * 4 + 4096;

    float* partial;
    int*   topk_ws;

    if (ws_size >= FAST_NEED) {
        // ---------------- fast path: LDS-free fragment-panel GEMMs ----------
        char* p = (char*)d_ws;
        ushort* a1p0 = (ushort*)p;  p += A1CH * 2;
        ushort* a1p1 = (ushort*)p;  p += A1CH * 2;
        ushort* h1p0 = (ushort*)p;  p += H1CH * 2;
        ushort* h1p1 = (ushort*)p;  p += H1CH * 2;
        ushort* w1p0 = (ushort*)p;  p += W1CH * 2;
        ushort* w1p1 = (ushort*)p;  p += W1CH * 2;
        ushort* w2p0 = (ushort*)p;  p += W2CH * 2;
        ushort* w2p1 = (ushort*)p;  p += W2CH * 2;
        partial      = (float*)p;   p += (size_t)NPART * M_ * 4;
        topk_ws      = (int*)p;

        split_a_panel<64><<<(M_ / 16) * 64 / 4, 256, 0, stream>>>(
            span_vecs, a1p0, a1p1);
        split_w_frag<64><<<(H_ / 16) * 64 * 64 / 256, 256, 0, stream>>>(
            W1, w1p0, w1p1);
        split_w_frag<32><<<(H_ / 16) * 32 * 64 / 256, 256, 0, stream>>>(
            W2, w2p0, w2p1);

        // 128x128 blocks: grid (n-blocks of 128, m-blocks of 128).
        gemm_frag<64, false><<<dim3(8, M_ / 128), 256, 0, stream>>>(
            a1p0, a1p1, w1p0, w1p1, b1, nullptr, nullptr, h1p0, h1p1);
        gemm_frag<32, true><<<dim3(8, M_ / 128), 256, 0, stream>>>(
            h1p0, h1p1, w2p0, w2p1, b2, W3, partial, nullptr, nullptr);
    } else {
        // ---------------- fallback: R2 path (proven, ~147 MB) ---------------
        float*  h1   = (float*)d_ws;
        partial      = h1 + (size_t)M_ * H_;
        ushort* w1p0 = (ushort*)(partial + (size_t)NPART * M_);
        ushort* w1p1 = w1p0 + (size_t)256 * 1024 * 8;
        ushort* w1p2 = w1p1 + (size_t)256 * 1024 * 8;
        ushort* w2p0 = w1p2 + (size_t)256 * 1024 * 8;
        ushort* w2p1 = w2p0 + (size_t)128 * 1024 * 8;
        ushort* w2p2 = w2p1 + (size_t)128 * 1024 * 8;
        topk_ws      = (int*)(w2p2 + (size_t)128 * 1024 * 8);

        split_w_panel<<<(256 * 1024) / 256, 256, 0, stream>>>(W1, w1p0, w1p1, w1p2, 256);
        split_w_panel<<<(128 * 1024) / 256, 256, 0, stream>>>(W2, w2p0, w2p1, w2p2, 128);
        gemm_split<2048, false><<<dim3(16, 120), 256, 0, stream>>>(
            span_vecs, w1p0, w1p1, w1p2, b1, nullptr, h1);
        gemm_split<1024, true><<<dim3(16, 120), 256, 0, stream>>>(
            h1, w2p0, w2p1, w2p2, b2, W3, partial);
    }

    topk_kernel<<<B_, 1024, 0, stream>>>(
        partial, span_mask, span_begin, span_end, seq_len, b3, out, topk_ws);
    gather_vecs<<<B_ * K_SPANS, 256, 0, stream>>>(span_vecs, topk_ws, out);
    masks_kernel<<<(B_ * K_SPANS * K_SPANS + 255) / 256, 256, 0, stream>>>(
        seq_len, out);
}

// Round 9
// 1180.189 us; speedup vs baseline: 1.1858x; 1.1858x over previous
//
#include <hip/hip_runtime.h>
#include <stdint.h>

// Problem constants (fixed by the reference)
#define B_ 4
#define T_ 512
#define L_ 15
#define D_ 2048
#define H_ 1024
#define TL_ (T_*L_)            // 7680
#define M_ (B_*TL_)            // 30720
#define K_SPANS 205
#define NSORT 8192
#define NPART 16               // score partials = H/64 column blocks

// d_out float offsets (outputs concatenated flat in return order)
#define OFF_PRUNE 0                                   // [B,T,L,1]  30720
#define OFF_TOP   (OFF_PRUNE + M_)                    // [B,K]      820
#define OFF_FVECS (OFF_TOP + B_*K_SPANS)              // [B,K,D]    1679360
#define OFF_FSC   (OFF_FVECS + B_*K_SPANS*D_)         // [B,K,1]
#define OFF_FBEG  (OFF_FSC + B_*K_SPANS)
#define OFF_FEND  (OFF_FBEG + B_*K_SPANS)
#define OFF_SL    (OFF_FEND + B_*K_SPANS)
#define OFF_SQ    (OFF_SL + B_)
#define OFF_TRI   (OFF_SQ + B_*K_SPANS*K_SPANS)

typedef __attribute__((ext_vector_type(8))) short s16x8;   // 8 bf16 = 4 VGPRs
typedef __attribute__((ext_vector_type(4))) float f32x4;   // MFMA C/D frag

// ---- exact fp32 -> bf16 split helpers (RNE) --------------------------------
__device__ __forceinline__ ushort bf16rne(float f) {
    uint u = __float_as_uint(f);
    return (ushort)((u + 0x7fffu + ((u >> 16) & 1u)) >> 16);
}
__device__ __forceinline__ float bfval(ushort h) {
    return __uint_as_float(((uint)h) << 16);
}
// 3-term split (fallback path only)
__device__ __forceinline__ void split1(float x, ushort& h0, ushort& h1, ushort& h2) {
    h0 = bf16rne(x);            float f0 = bfval(h0);
    float r = x - f0;           h1 = bf16rne(r);
    float r2 = r - bfval(h1);   h2 = bf16rne(r2);
}
__device__ __forceinline__ void split4(float4 v, uint2& q0, uint2& q1, uint2& q2) {
    ushort a0[4], a1[4], a2[4];
    float x[4] = {v.x, v.y, v.z, v.w};
    #pragma unroll
    for (int j = 0; j < 4; ++j) split1(x[j], a0[j], a1[j], a2[j]);
    q0 = make_uint2((uint)a0[0] | ((uint)a0[1] << 16), (uint)a0[2] | ((uint)a0[3] << 16));
    q1 = make_uint2((uint)a1[0] | ((uint)a1[1] << 16), (uint)a1[2] | ((uint)a1[3] << 16));
    q2 = make_uint2((uint)a2[0] | ((uint)a2[1] << 16), (uint)a2[2] | ((uint)a2[3] << 16));
}
// 2-term split (fast path): x ~= bf(h0) + bf(h1), residual <= 2^-18 |x|.
// Validated R4: absmax 0.00098 (same as 3-term), dur -38%.
__device__ __forceinline__ void split2(float x, ushort& h0, ushort& h1) {
    h0 = bf16rne(x);            float f0 = bfval(h0);
    h1 = bf16rne(x - f0);
}
__device__ __forceinline__ void split4_2(float4 v, uint2& q0, uint2& q1) {
    ushort a0[4], a1[4];
    float x[4] = {v.x, v.y, v.z, v.w};
    #pragma unroll
    for (int j = 0; j < 4; ++j) split2(x[j], a0[j], a1[j]);
    q0 = make_uint2((uint)a0[0] | ((uint)a0[1] << 16), (uint)a0[2] | ((uint)a0[3] << 16));
    q1 = make_uint2((uint)a1[0] | ((uint)a1[1] << 16), (uint)a1[2] | ((uint)a1[3] << 16));
}

__device__ __forceinline__ f32x4 mfma16(s16x8 a, s16x8 b, f32x4 c) {
    return __builtin_amdgcn_mfma_f32_16x16x32_bf16(a, b, c, 0, 0, 0);
}

// ===========================================================================
// FAST PATH — 2-panel split-bf16 (R5-proven core: 1177us total).
// Geometry history: 256m x 64n blocks, dim3(16,120), rot=(w+bx+by) is the
// BEST measured config. Refuted alternatives: phase-align w/o bx (R1, -6%),
// XCD-grouping (R2, -25%), 3->2 MFMA thinning (R6, -8%), 128x128 blocks
// (R8: FETCH 1.22->2.07 GB — B panels 8.4MB > 4MB/XCD L2 thrash at 128-col
// blocks; A instr-read halving didn't compensate). Traffic model: FETCH =
// A-panel bytes x 16 sharers x ~30% L2 miss; only byte-shrinking moved it.
// Panels are stored in MFMA fragment-tile layout:
//   tile = (row16_idx * K32 + g), 1024 B per tile,
//   lane l (l=0..63) owns 8 bf16 at tile*1024 + l*16:
//     A-panel: A[row16*16 + (l&15)][g*32 + (l>>4)*8 + j]
//     B-panel: W[g*32 + (l>>4)*8 + j][n16*16 + (l&15)]
// ===========================================================================

// A [ROWS, K32*32] fp32 row-major -> 2 split panels in frag-tile layout.
template<int K32>
__global__ __launch_bounds__(256) void split_a_panel(
    const float* __restrict__ A, ushort* __restrict__ P0,
    ushort* __restrict__ P1)
{
    const int l    = threadIdx.x & 63;
    const int w    = threadIdx.x >> 6;
    const int tile = blockIdx.x * 4 + w;
    const int r16  = tile / K32;
    const int g    = tile % K32;
    const int row  = r16 * 16 + (l & 15);
    const int k0   = g * 32 + (l >> 4) * 8;
    const float* src = A + (size_t)row * (K32 * 32) + k0;
    float4 v0 = *(const float4*)src;
    float4 v1 = *(const float4*)(src + 4);
    uint2 a0, a1, b0, b1;
    split4_2(v0, a0, a1);
    split4_2(v1, b0, b1);
    const size_t off = ((size_t)tile * 64 + l) * 8;
    *(uint4*)(P0 + off) = make_uint4(a0.x, a0.y, b0.x, b0.y);
    *(uint4*)(P1 + off) = make_uint4(a1.x, a1.y, b1.x, b1.y);
}

// W [K32*32, 1024] fp32 -> 2 split panels in frag-tile layout (B-operand).
template<int K32>
__global__ __launch_bounds__(256) void split_w_frag(
    const float* __restrict__ W, ushort* __restrict__ P0,
    ushort* __restrict__ P1)
{
    const int idx  = blockIdx.x * 256 + threadIdx.x;
    const int l    = idx & 63;
    const int tile = idx >> 6;
    const int n16  = tile / K32;
    const int g    = tile % K32;
    const int n    = n16 * 16 + (l & 15);
    const int kb   = g * 32 + (l >> 4) * 8;
    ushort h0[8], h1[8];
    #pragma unroll
    for (int j = 0; j < 8; ++j) {
        float wv = W[(size_t)(kb + j) * 1024 + n];
        split2(wv, h0[j], h1[j]);
    }
    const size_t off = (size_t)idx * 8;
    *(uint4*)(P0 + off) = *(uint4*)h0;
    *(uint4*)(P1 + off) = *(uint4*)h1;
}

// LDS-free split-bf16 MFMA GEMM, fragments straight from panels.
// Block = 4 waves stacked in m; wave tile 64m x 64n; 64 MFMA per k32 step.
// R9: R5 config + __launch_bounds__(256, 3) — guarantee 3 blocks/CU
// (was ~2.4, Occupancy 30%). 140 regs/thread fits 3 waves/SIMD (<=170);
// LDS 16.9KB x 3 << 160KB. +25% resident waves -> more outstanding loads
// -> higher sustained BW (the binding term: dur = 1.22GB / achieved-BW).
template<int K32, bool FUSE>
__global__ __launch_bounds__(256, 3) void gemm_frag(
    const ushort* __restrict__ Ap0, const ushort* __restrict__ Ap1,
    const ushort* __restrict__ Bp0, const ushort* __restrict__ Bp1,
    const float* __restrict__ bias, const float* __restrict__ W3,
    float* __restrict__ outF, ushort* __restrict__ outP0,
    ushort* __restrict__ outP1)
{
    const int tid = threadIdx.x;
    const int l   = tid & 63;
    const int w   = tid >> 6;
    const int lr  = l & 15;
    const int lq  = l >> 4;
    const int mb  = blockIdx.y * 16 + w * 4;   // base m16-tile (4 per wave)
    const int nb  = blockIdx.x * 4;            // base n16-tile
    const int n0  = blockIdx.x * 64;

    size_t aoff[4], boff[4];
    #pragma unroll
    for (int t = 0; t < 4; ++t) {
        aoff[t] = ((size_t)(mb + t) * K32 * 64 + l) * 8;
        boff[t] = ((size_t)(nb + t) * K32 * 64 + l) * 8;
    }

    f32x4 acc[4][4] = {};

    const int rot = ((w + blockIdx.x + blockIdx.y) & 3) * (K32 / 4);

    for (int gi = 0; gi < K32; ++gi) {
        int g = gi + rot;
        g -= (g >= K32) ? K32 : 0;
        s16x8 A0[4], A1[4], B0[4], B1[4];
        const size_t gofs = (size_t)g * 512;
        #pragma unroll
        for (int t = 0; t < 4; ++t) {
            const size_t ao = aoff[t] + gofs;
            const size_t bo = boff[t] + gofs;
            A0[t] = *(const s16x8*)(Ap0 + ao);
            A1[t] = *(const s16x8*)(Ap1 + ao);
            B0[t] = *(const s16x8*)(Bp0 + bo);
            B1[t] = *(const s16x8*)(Bp1 + bo);
        }
        #pragma unroll
        for (int mt = 0; mt < 4; ++mt)
            #pragma unroll
            for (int nt = 0; nt < 4; ++nt) {
                f32x4 c = acc[mt][nt];
                c = mfma16(A0[mt], B0[nt], c);
                c = mfma16(A0[mt], B1[nt], c);
                c = mfma16(A1[mt], B0[nt], c);
                c = mfma16(A1[mt], B1[nt], c);
                acc[mt][nt] = c;
            }
    }

    // C/D layout: col = lane&15, row = (lane>>4)*4 + reg  [m89-verified]
    float bv[4];
    #pragma unroll
    for (int nt = 0; nt < 4; ++nt) bv[nt] = bias[n0 + nt * 16 + lr];

    if (!FUSE) {
        // Fused relu + 2-term split + h1-panel write (R5-proven).
        __shared__ float sT[4][16][65];
        const int KH32 = 32;                   // h1 panels: K32 = H/32
        #pragma unroll
        for (int mt = 0; mt < 4; ++mt) {
            #pragma unroll
            for (int nt = 0; nt < 4; ++nt)
                #pragma unroll
                for (int r = 0; r < 4; ++r)
                    sT[w][lq * 4 + r][nt * 16 + lr] =
                        fmaxf(acc[mt][nt][r] + bv[nt], 0.f);
            __syncthreads();
            const int r16 = mb + mt;
            #pragma unroll
            for (int gg = 0; gg < 2; ++gg) {
                ushort h0[8], h1v[8];
                #pragma unroll
                for (int jj = 0; jj < 8; ++jj) {
                    float v = sT[w][lr][gg * 32 + lq * 8 + jj];
                    split2(v, h0[jj], h1v[jj]);
                }
                const size_t off =
                    ((size_t)(r16 * KH32 + blockIdx.x * 2 + gg) * 64 + l) * 8;
                *(uint4*)(outP0 + off) = *(uint4*)h0;
                *(uint4*)(outP1 + off) = *(uint4*)h1v;
            }
            __syncthreads();
        }
    } else {
        float wv[4];
        #pragma unroll
        for (int nt = 0; nt < 4; ++nt) wv[nt] = W3[n0 + nt * 16 + lr];
        #pragma unroll
        for (int mt = 0; mt < 4; ++mt)
            #pragma unroll
            for (int r = 0; r < 4; ++r) {
                float v = 0.f;
                #pragma unroll
                for (int nt = 0; nt < 4; ++nt)
                    v += fmaxf(acc[mt][nt][r] + bv[nt], 0.f) * wv[nt];
                v += __shfl_xor(v, 1);
                v += __shfl_xor(v, 2);
                v += __shfl_xor(v, 4);
                v += __shfl_xor(v, 8);
                if (lr == 0)
                    outF[(size_t)blockIdx.x * M_ + (mb + mt) * 16 + lq * 4 + r] = v;
            }
    }
}

// ===========================================================================
// FALLBACK PATH (R2, ~147 MB ws) — unchanged, proven correct.
// ===========================================================================
__global__ void split_w_panel(const float* __restrict__ W, ushort* __restrict__ P0,
                              ushort* __restrict__ P1, ushort* __restrict__ P2, int K8)
{
    const int idx = blockIdx.x * 256 + threadIdx.x;
    if (idx >= K8 * 1024) return;
    const int k8 = idx >> 10;
    const int n  = idx & 1023;
    ushort h0[8], h1[8], h2[8];
    #pragma unroll
    for (int j = 0; j < 8; ++j) {
        float w = W[(size_t)(k8 * 8 + j) * 1024 + n];
        split1(w, h0[j], h1[j], h2[j]);
    }
    *(uint4*)(P0 + (size_t)idx * 8) = *(uint4*)h0;
    *(uint4*)(P1 + (size_t)idx * 8) = *(uint4*)h1;
    *(uint4*)(P2 + (size_t)idx * 8) = *(uint4*)h2;
}

template<int KDIM, bool FUSE>
__global__ __launch_bounds__(256, 2) void gemm_split(
    const float* __restrict__ A,
    const ushort* __restrict__ P0, const ushort* __restrict__ P1,
    const ushort* __restrict__ P2,
    const float* __restrict__ bias, const float* __restrict__ W3,
    float* __restrict__ out)
{
    __shared__ ushort aLds[3][4 * 257 * 8];
    __shared__ ushort bLds[3][4 * 65 * 8];

    const int tid   = threadIdx.x;
    const int lane  = tid & 63;
    const int lr    = lane & 15;
    const int lq    = lane >> 4;
    const int waveM = (tid >> 6) * 64;
    const int m0    = blockIdx.y * 256;
    const int n0    = blockIdx.x * 64;

    const int bq = tid >> 6;
    const int bn = tid & 63;
    const int ar = tid >> 3;
    const int ac4 = tid & 7;

    f32x4 acc[4][4] = {};

    for (int kt = 0; kt < KDIM / 32; ++kt) {
        const int k80 = kt * 4;
        const size_t bchunk = ((size_t)(k80 + bq) * 1024 + n0 + bn) * 8;
        uint4 bf0 = *(const uint4*)(P0 + bchunk);
        uint4 bf1 = *(const uint4*)(P1 + bchunk);
        uint4 bf2 = *(const uint4*)(P2 + bchunk);
        float4 av[8];
        #pragma unroll
        for (int sw = 0; sw < 8; ++sw) {
            const int row = sw * 32 + ar;
            av[sw] = *(const float4*)(A + (size_t)(m0 + row) * KDIM + kt * 32 + ac4 * 4);
        }
        __syncthreads();
        *(uint4*)&bLds[0][(bq * 65 + bn) * 8] = bf0;
        *(uint4*)&bLds[1][(bq * 65 + bn) * 8] = bf1;
        *(uint4*)&bLds[2][(bq * 65 + bn) * 8] = bf2;
        #pragma unroll
        for (int sw = 0; sw < 8; ++sw) {
            const int row = sw * 32 + ar;
            uint2 q0, q1, q2;
            split4(av[sw], q0, q1, q2);
            const int off = ((ac4 >> 1) * 257 + row) * 8 + (ac4 & 1) * 4;
            *(uint2*)&aLds[0][off] = q0;
            *(uint2*)&aLds[1][off] = q1;
            *(uint2*)&aLds[2][off] = q2;
        }
        __syncthreads();

        s16x8 B0[4], B1[4], B2[4];
        #pragma unroll
        for (int nt = 0; nt < 4; ++nt) {
            const int boff = (lq * 65 + nt * 16 + lr) * 8;
            B0[nt] = *(const s16x8*)&bLds[0][boff];
            B1[nt] = *(const s16x8*)&bLds[1][boff];
            B2[nt] = *(const s16x8*)&bLds[2][boff];
        }
        #pragma unroll
        for (int mt = 0; mt < 4; ++mt) {
            const int aoff = (lq * 257 + waveM + mt * 16 + lr) * 8;
            s16x8 A0 = *(const s16x8*)&aLds[0][aoff];
            s16x8 A1 = *(const s16x8*)&aLds[1][aoff];
            s16x8 A2 = *(const s16x8*)&aLds[2][aoff];
            #pragma unroll
            for (int nt = 0; nt < 4; ++nt) {
                f32x4 c = acc[mt][nt];
                c = mfma16(A0, B0[nt], c);
                c = mfma16(A0, B1[nt], c);
                c = mfma16(A1, B0[nt], c);
                c = mfma16(A1, B1[nt], c);
                c = mfma16(A0, B2[nt], c);
                c = mfma16(A2, B0[nt], c);
                acc[mt][nt] = c;
            }
        }
    }

    float bv[4];
    #pragma unroll
    for (int nt = 0; nt < 4; ++nt) bv[nt] = bias[n0 + nt * 16 + lr];

    if (!FUSE) {
        #pragma unroll
        for (int mt = 0; mt < 4; ++mt)
            #pragma unroll
            for (int nt = 0; nt < 4; ++nt)
                #pragma unroll
                for (int r = 0; r < 4; ++r) {
                    const int row = m0 + waveM + mt * 16 + lq * 4 + r;
                    out[(size_t)row * 1024 + n0 + nt * 16 + lr] =
                        fmaxf(acc[mt][nt][r] + bv[nt], 0.f);
                }
    } else {
        float wv[4];
        #pragma unroll
        for (int nt = 0; nt < 4; ++nt) wv[nt] = W3[n0 + nt * 16 + lr];
        #pragma unroll
        for (int mt = 0; mt < 4; ++mt)
            #pragma unroll
            for (int r = 0; r < 4; ++r) {
                float v = 0.f;
                #pragma unroll
                for (int nt = 0; nt < 4; ++nt)
                    v += fmaxf(acc[mt][nt][r] + bv[nt], 0.f) * wv[nt];
                v += __shfl_xor(v, 1);
                v += __shfl_xor(v, 2);
                v += __shfl_xor(v, 4);
                v += __shfl_xor(v, 8);
                if (lr == 0)
                    out[(size_t)blockIdx.x * M_ + m0 + waveM + mt * 16 + lq * 4 + r] = v;
            }
    }
}

// ===========================================================================
// Top-K / gather / masks (shared by both paths)
// ===========================================================================
__device__ __forceinline__ uint64_t score_key(float s, int idx) {
    unsigned u = __float_as_uint(s);
    u = (u & 0x80000000u) ? ~u : (u | 0x80000000u);
    return ((uint64_t)u << 32) | (uint64_t)(0xFFFFFFFFu - (unsigned)idx);
}

__device__ __forceinline__ float compute_score(
    const float* __restrict__ partial, const float* __restrict__ mask,
    float b3v, int b, int i)
{
    const int m = b * TL_ + i;
    float s = b3v;
    #pragma unroll
    for (int cb = 0; cb < NPART; ++cb) s += partial[(size_t)cb * M_ + m];
    s -= (1.0f - mask[m]) * 10000.0f;
    return s;
}

__global__ __launch_bounds__(1024) void topk_kernel(
    const float* __restrict__ partial, const float* __restrict__ span_mask,
    const int* __restrict__ span_begin, const int* __restrict__ span_end,
    const int* __restrict__ seq_len, const float* __restrict__ b3,
    float* __restrict__ out, int* __restrict__ topk_ws)
{
    __shared__ uint64_t keys[NSORT];
    const int tid = threadIdx.x;
    const int b   = blockIdx.x;
    const float b3v = b3[0];

    for (int i = tid; i < NSORT; i += 1024) {
        if (i < TL_) {
            float s = compute_score(partial, span_mask, b3v, b, i);
            out[OFF_PRUNE + b * TL_ + i] = s;
            keys[i] = score_key(s, i);
        } else {
            keys[i] = 0ull;
        }
    }
    __syncthreads();

    for (unsigned kk = 2; kk <= NSORT; kk <<= 1) {
        for (unsigned j = kk >> 1; j > 0; j >>= 1) {
            for (unsigned i = (unsigned)tid; i < NSORT; i += 1024) {
                unsigned ixj = i ^ j;
                if (ixj > i) {
                    uint64_t x = keys[i], y = keys[ixj];
                    bool desc = ((i & kk) == 0);
                    if (desc ? (x < y) : (x > y)) { keys[i] = y; keys[ixj] = x; }
                }
            }
            __syncthreads();
        }
    }

    const uint64_t cutoff = keys[K_SPANS - 1];
    __syncthreads();

    unsigned* sScan = (unsigned*)keys;
    unsigned base = 0;
    const unsigned lane = tid & 63;
    const unsigned wv   = tid >> 6;
    for (int c = 0; c < TL_; c += 1024) {
        const int i = c + tid;
        bool flag = false; float s = 0.f;
        if (i < TL_) {
            // Read back the score stored in pass 1 (bitwise identical).
            s = out[OFF_PRUNE + b * TL_ + i];
            flag = (score_key(s, i) >= cutoff);
        }
        uint64_t bal = __ballot(flag);
        unsigned pre = (unsigned)__popcll(bal & ((1ull << lane) - 1ull));
        if (lane == 0) sScan[wv] = (unsigned)__popcll(bal);
        __syncthreads();
        unsigned woff = 0, tot = 0;
        for (int w = 0; w < 16; ++w) {
            unsigned v = sScan[w];
            if (w < (int)wv) woff += v;
            tot += v;
        }
        if (flag) {
            const int g = b * K_SPANS + (int)(base + woff + pre);
            topk_ws[g]        = i;
            out[OFF_TOP + g]  = (float)i;
            out[OFF_FSC + g]  = s;
            out[OFF_FBEG + g] = (float)span_begin[b * TL_ + i];
            out[OFF_FEND + g] = (float)span_end[b * TL_ + i];
        }
        base += tot;
        __syncthreads();
    }

    if (tid == 0)
        out[OFF_SL + b] = ceilf(0.4f * (float)seq_len[b]);
}

__global__ void gather_vecs(const float* __restrict__ span_vecs,
                            const int* __restrict__ topk_ws,
                            float* __restrict__ out)
{
    const int bk  = blockIdx.x;
    const int b   = bk / K_SPANS;
    const int row = topk_ws[bk];
    const float4* src = (const float4*)(span_vecs + ((size_t)b * TL_ + row) * D_);
    float4* dst = (float4*)(out + OFF_FVECS + (size_t)bk * D_);
    for (int j = threadIdx.x; j < D_ / 4; j += blockDim.x) dst[j] = src[j];
}

__global__ void masks_kernel(const int* __restrict__ seq_len,
                             float* __restrict__ out)
{
    const int idx = blockIdx.x * blockDim.x + threadIdx.x;
    if (idx >= B_ * K_SPANS * K_SPANS) return;
    const int b = idx / (K_SPANS * K_SPANS);
    const int r = idx - b * K_SPANS * K_SPANS;
    const int i = r / K_SPANS;
    const int j = r - i * K_SPANS;
    const int sl = (int)ceilf(0.4f * (float)seq_len[b]);
    const float v = (i < sl && j < sl) ? 1.0f : 0.0f;
    out[OFF_SQ + idx]  = v;
    out[OFF_TRI + idx] = (j <= i) ? v : 0.0f;
}

// ===========================================================================
extern "C" void kernel_launch(void* const* d_in, const int* in_sizes, int n_in,
                              void* d_out, int out_size, void* d_ws, size_t ws_size,
                              hipStream_t stream)
{
    const float* span_vecs  = (const float*)d_in[0];
    const float* span_mask  = (const float*)d_in[1];
    const int*   span_begin = (const int*)  d_in[2];
    const int*   span_end   = (const int*)  d_in[3];
    const int*   seq_len    = (const int*)  d_in[4];
    const float* W1 = (const float*)d_in[5];
    const float* b1 = (const float*)d_in[6];
    const float* W2 = (const float*)d_in[7];
    const float* b2 = (const float*)d_in[8];
    const float* W3 = (const float*)d_in[9];
    const float* b3 = (const float*)d_in[10];
    float* out = (float*)d_out;

    const size_t A1CH = (size_t)M_ * D_;        // ushorts per A1 panel chunk
    const size_t H1CH = (size_t)M_ * H_;        // ushorts per h1 panel chunk
    const size_t W1CH = (size_t)D_ * H_;        // ushorts per W1 panel chunk
    const size_t W2CH = (size_t)H_ * H_;        // ushorts per W2 panel chunk
    const size_t FAST_NEED =
        2 * A1CH * 2 + 2 * H1CH * 2 +
        2 * W1CH * 2 + 2 * W2CH * 2 + (size_t)NPART * M_ * 4 + 4096;

    float* partial;
    int*   topk_ws;

    if (ws_size >= FAST_NEED) {
        // ---------------- fast path: LDS-free fragment-panel GEMMs ----------
        char* p = (char*)d_ws;
        ushort* a1p0 = (ushort*)p;  p += A1CH * 2;
        ushort* a1p1 = (ushort*)p;  p += A1CH * 2;
        ushort* h1p0 = (ushort*)p;  p += H1CH * 2;
        ushort* h1p1 = (ushort*)p;  p += H1CH * 2;
        ushort* w1p0 = (ushort*)p;  p += W1CH * 2;
        ushort* w1p1 = (ushort*)p;  p += W1CH * 2;
        ushort* w2p0 = (ushort*)p;  p += W2CH * 2;
        ushort* w2p1 = (ushort*)p;  p += W2CH * 2;
        partial      = (float*)p;   p += (size_t)NPART * M_ * 4;
        topk_ws      = (int*)p;

        split_a_panel<64><<<(M_ / 16) * 64 / 4, 256, 0, stream>>>(
            span_vecs, a1p0, a1p1);
        split_w_frag<64><<<(H_ / 16) * 64 * 64 / 256, 256, 0, stream>>>(
            W1, w1p0, w1p1);
        split_w_frag<32><<<(H_ / 16) * 32 * 64 / 256, 256, 0, stream>>>(
            W2, w2p0, w2p1);

        // GEMM1 writes h1 bf16 panels directly (fused relu+split epilogue).
        gemm_frag<64, false><<<dim3(16, M_ / 256), 256, 0, stream>>>(
            a1p0, a1p1, w1p0, w1p1, b1, nullptr, nullptr, h1p0, h1p1);
        gemm_frag<32, true><<<dim3(16, M_ / 256), 256, 0, stream>>>(
            h1p0, h1p1, w2p0, w2p1, b2, W3, partial, nullptr, nullptr);
    } else {
        // ---------------- fallback: R2 path (proven, ~147 MB) ---------------
        float*  h1   = (float*)d_ws;
        partial      = h1 + (size_t)M_ * H_;
        ushort* w1p0 = (ushort*)(partial + (size_t)NPART * M_);
        ushort* w1p1 = w1p0 + (size_t)256 * 1024 * 8;
        ushort* w1p2 = w1p1 + (size_t)256 * 1024 * 8;
        ushort* w2p0 = w1p2 + (size_t)256 * 1024 * 8;
        ushort* w2p1 = w2p0 + (size_t)128 * 1024 * 8;
        ushort* w2p2 = w2p1 + (size_t)128 * 1024 * 8;
        topk_ws      = (int*)(w2p2 + (size_t)128 * 1024 * 8);

        split_w_panel<<<(256 * 1024) / 256, 256, 0, stream>>>(W1, w1p0, w1p1, w1p2, 256);
        split_w_panel<<<(128 * 1024) / 256, 256, 0, stream>>>(W2, w2p0, w2p1, w2p2, 128);
        gemm_split<2048, false><<<dim3(16, 120), 256, 0, stream>>>(
            span_vecs, w1p0, w1p1, w1p2, b1, nullptr, h1);
        gemm_split<1024, true><<<dim3(16, 120), 256, 0, stream>>>(
            h1, w2p0, w2p1, w2p2, b2, W3, partial);
    }

    topk_kernel<<<B_, 1024, 0, stream>>>(
        partial, span_mask, span_begin, span_end, seq_len, b3, out, topk_ws);
    gather_vecs<<<B_ * K_SPANS, 256, 0, stream>>>(span_vecs, topk_ws, out);
    masks_kernel<<<(B_ * K_SPANS * K_SPANS + 255) / 256, 256, 0, stream>>>(
        seq_len, out);
}

// Round 10
// 1165.800 us; speedup vs baseline: 1.2004x; 1.0123x over previous
//
#include <hip/hip_runtime.h>
#include <stdint.h>

// Problem constants (fixed by the reference)
#define B_ 4
#define T_ 512
#define L_ 15
#define D_ 2048
#define H_ 1024
#define TL_ (T_*L_)            // 7680
#define M_ (B_*TL_)            // 30720
#define K_SPANS 205
#define NSORT 8192
#define NPART 16               // score partials = H/64 column blocks

// d_out float offsets (outputs concatenated flat in return order)
#define OFF_PRUNE 0                                   // [B,T,L,1]  30720
#define OFF_TOP   (OFF_PRUNE + M_)                    // [B,K]      820
#define OFF_FVECS (OFF_TOP + B_*K_SPANS)              // [B,K,D]    1679360
#define OFF_FSC   (OFF_FVECS + B_*K_SPANS*D_)         // [B,K,1]
#define OFF_FBEG  (OFF_FSC + B_*K_SPANS)
#define OFF_FEND  (OFF_FBEG + B_*K_SPANS)
#define OFF_SL    (OFF_FEND + B_*K_SPANS)
#define OFF_SQ    (OFF_SL + B_)
#define OFF_TRI   (OFF_SQ + B_*K_SPANS*K_SPANS)

typedef __attribute__((ext_vector_type(8))) short s16x8;   // 8 bf16 = 4 VGPRs
typedef __attribute__((ext_vector_type(4))) float f32x4;   // MFMA C/D frag
typedef __attribute__((ext_vector_type(4))) uint  u32x4;   // 16B nt-store unit

// ---- non-temporal helpers (bit-exact; cache-policy only) -------------------
// R10: panel writes have ZERO reuse within the producing kernel (consumed by
// the NEXT kernel after a full barrier). Streaming them write-allocate
// through L2/L3 evicts A-panel lines that 16 sharer-blocks still need
// (A-panels 252MB ~ entire 256MB L3; measured 0.95GB of capacity misses
// above the cold floor). nt stores/loads remove that pollution.
__device__ __forceinline__ void nt_store16(void* p, u32x4 v) {
    __builtin_nontemporal_store(v, (u32x4*)p);
}
__device__ __forceinline__ f32x4 nt_load_f4(const void* p) {
    return __builtin_nontemporal_load((const f32x4*)p);
}

// ---- exact fp32 -> bf16 split helpers (RNE) --------------------------------
__device__ __forceinline__ ushort bf16rne(float f) {
    uint u = __float_as_uint(f);
    return (ushort)((u + 0x7fffu + ((u >> 16) & 1u)) >> 16);
}
__device__ __forceinline__ float bfval(ushort h) {
    return __uint_as_float(((uint)h) << 16);
}
// 3-term split (fallback path only)
__device__ __forceinline__ void split1(float x, ushort& h0, ushort& h1, ushort& h2) {
    h0 = bf16rne(x);            float f0 = bfval(h0);
    float r = x - f0;           h1 = bf16rne(r);
    float r2 = r - bfval(h1);   h2 = bf16rne(r2);
}
__device__ __forceinline__ void split4(float4 v, uint2& q0, uint2& q1, uint2& q2) {
    ushort a0[4], a1[4], a2[4];
    float x[4] = {v.x, v.y, v.z, v.w};
    #pragma unroll
    for (int j = 0; j < 4; ++j) split1(x[j], a0[j], a1[j], a2[j]);
    q0 = make_uint2((uint)a0[0] | ((uint)a0[1] << 16), (uint)a0[2] | ((uint)a0[3] << 16));
    q1 = make_uint2((uint)a1[0] | ((uint)a1[1] << 16), (uint)a1[2] | ((uint)a1[3] << 16));
    q2 = make_uint2((uint)a2[0] | ((uint)a2[1] << 16), (uint)a2[2] | ((uint)a2[3] << 16));
}
// 2-term split (fast path): x ~= bf(h0) + bf(h1), residual <= 2^-18 |x|.
// Validated R4: absmax 0.00098 (same as 3-term), dur -38%.
__device__ __forceinline__ void split2(float x, ushort& h0, ushort& h1) {
    h0 = bf16rne(x);            float f0 = bfval(h0);
    h1 = bf16rne(x - f0);
}
__device__ __forceinline__ void split4_2v(f32x4 v, uint2& q0, uint2& q1) {
    ushort a0[4], a1[4];
    #pragma unroll
    for (int j = 0; j < 4; ++j) split2(v[j], a0[j], a1[j]);
    q0 = make_uint2((uint)a0[0] | ((uint)a0[1] << 16), (uint)a0[2] | ((uint)a0[3] << 16));
    q1 = make_uint2((uint)a1[0] | ((uint)a1[1] << 16), (uint)a1[2] | ((uint)a1[3] << 16));
}

__device__ __forceinline__ f32x4 mfma16(s16x8 a, s16x8 b, f32x4 c) {
    return __builtin_amdgcn_mfma_f32_16x16x32_bf16(a, b, c, 0, 0, 0);
}

// ===========================================================================
// FAST PATH — 2-panel split-bf16 (R5-proven core: 1177us total).
// Geometry history: 256m x 64n blocks, dim3(16,120), rot=(w+bx+by) is the
// BEST measured config. Refuted alternatives: phase-align w/o bx (R1, -6%),
// XCD-grouping (R2, -25%), 3->2 MFMA thinning (R6, -8%), 128x128 blocks
// (R8, FETCH +70%), launch_bounds(256,3) (R9, exact null — occupancy is
// dispatch-limited at ~2.4 blk/CU, not register-limited; 4 waves/SIMD needs
// <=128 regs vs ~134 live: structurally blocked).
// Panels are stored in MFMA fragment-tile layout:
//   tile = (row16_idx * K32 + g), 1024 B per tile,
//   lane l (l=0..63) owns 8 bf16 at tile*1024 + l*16:
//     A-panel: A[row16*16 + (l&15)][g*32 + (l>>4)*8 + j]
//     B-panel: W[g*32 + (l>>4)*8 + j][n16*16 + (l&15)]
// ===========================================================================

// A [ROWS, K32*32] fp32 row-major -> 2 split panels in frag-tile layout.
// R10: nt loads (span_vecs read-once here) + nt stores (panels consumed by
// the next kernel only).
template<int K32>
__global__ __launch_bounds__(256) void split_a_panel(
    const float* __restrict__ A, ushort* __restrict__ P0,
    ushort* __restrict__ P1)
{
    const int l    = threadIdx.x & 63;
    const int w    = threadIdx.x >> 6;
    const int tile = blockIdx.x * 4 + w;
    const int r16  = tile / K32;
    const int g    = tile % K32;
    const int row  = r16 * 16 + (l & 15);
    const int k0   = g * 32 + (l >> 4) * 8;
    const float* src = A + (size_t)row * (K32 * 32) + k0;
    f32x4 v0 = nt_load_f4(src);
    f32x4 v1 = nt_load_f4(src + 4);
    uint2 a0, a1, b0, b1;
    split4_2v(v0, a0, a1);
    split4_2v(v1, b0, b1);
    const size_t off = ((size_t)tile * 64 + l) * 8;
    u32x4 p0; p0[0] = a0.x; p0[1] = a0.y; p0[2] = b0.x; p0[3] = b0.y;
    u32x4 p1; p1[0] = a1.x; p1[1] = a1.y; p1[2] = b1.x; p1[3] = b1.y;
    nt_store16(P0 + off, p0);
    nt_store16(P1 + off, p1);
}

// W [K32*32, 1024] fp32 -> 2 split panels in frag-tile layout (B-operand).
template<int K32>
__global__ __launch_bounds__(256) void split_w_frag(
    const float* __restrict__ W, ushort* __restrict__ P0,
    ushort* __restrict__ P1)
{
    const int idx  = blockIdx.x * 256 + threadIdx.x;
    const int l    = idx & 63;
    const int tile = idx >> 6;
    const int n16  = tile / K32;
    const int g    = tile % K32;
    const int n    = n16 * 16 + (l & 15);
    const int kb   = g * 32 + (l >> 4) * 8;
    ushort h0[8], h1[8];
    #pragma unroll
    for (int j = 0; j < 8; ++j) {
        float wv = W[(size_t)(kb + j) * 1024 + n];
        split2(wv, h0[j], h1[j]);
    }
    const size_t off = (size_t)idx * 8;
    nt_store16(P0 + off, *(const u32x4*)h0);
    nt_store16(P1 + off, *(const u32x4*)h1);
}

// LDS-free split-bf16 MFMA GEMM, fragments straight from panels.
// Block = 4 waves stacked in m; wave tile 64m x 64n; 64 MFMA per k32 step.
// A/B panel LOADS stay cached (16-sharer reuse). Epilogue h1-panel STORES
// are nt (zero reuse until GEMM2).
template<int K32, bool FUSE>
__global__ __launch_bounds__(256, 2) void gemm_frag(
    const ushort* __restrict__ Ap0, const ushort* __restrict__ Ap1,
    const ushort* __restrict__ Bp0, const ushort* __restrict__ Bp1,
    const float* __restrict__ bias, const float* __restrict__ W3,
    float* __restrict__ outF, ushort* __restrict__ outP0,
    ushort* __restrict__ outP1)
{
    const int tid = threadIdx.x;
    const int l   = tid & 63;
    const int w   = tid >> 6;
    const int lr  = l & 15;
    const int lq  = l >> 4;
    const int mb  = blockIdx.y * 16 + w * 4;   // base m16-tile (4 per wave)
    const int nb  = blockIdx.x * 4;            // base n16-tile
    const int n0  = blockIdx.x * 64;

    size_t aoff[4], boff[4];
    #pragma unroll
    for (int t = 0; t < 4; ++t) {
        aoff[t] = ((size_t)(mb + t) * K32 * 64 + l) * 8;
        boff[t] = ((size_t)(nb + t) * K32 * 64 + l) * 8;
    }

    f32x4 acc[4][4] = {};

    const int rot = ((w + blockIdx.x + blockIdx.y) & 3) * (K32 / 4);

    for (int gi = 0; gi < K32; ++gi) {
        int g = gi + rot;
        g -= (g >= K32) ? K32 : 0;
        s16x8 A0[4], A1[4], B0[4], B1[4];
        const size_t gofs = (size_t)g * 512;
        #pragma unroll
        for (int t = 0; t < 4; ++t) {
            const size_t ao = aoff[t] + gofs;
            const size_t bo = boff[t] + gofs;
            A0[t] = *(const s16x8*)(Ap0 + ao);
            A1[t] = *(const s16x8*)(Ap1 + ao);
            B0[t] = *(const s16x8*)(Bp0 + bo);
            B1[t] = *(const s16x8*)(Bp1 + bo);
        }
        #pragma unroll
        for (int mt = 0; mt < 4; ++mt)
            #pragma unroll
            for (int nt = 0; nt < 4; ++nt) {
                f32x4 c = acc[mt][nt];
                c = mfma16(A0[mt], B0[nt], c);
                c = mfma16(A0[mt], B1[nt], c);
                c = mfma16(A1[mt], B0[nt], c);
                c = mfma16(A1[mt], B1[nt], c);
                acc[mt][nt] = c;
            }
    }

    // C/D layout: col = lane&15, row = (lane>>4)*4 + reg  [m89-verified]
    float bv[4];
    #pragma unroll
    for (int nt = 0; nt < 4; ++nt) bv[nt] = bias[n0 + nt * 16 + lr];

    if (!FUSE) {
        // Fused relu + 2-term split + h1-panel write (R5-proven), nt stores.
        __shared__ float sT[4][16][65];
        const int KH32 = 32;                   // h1 panels: K32 = H/32
        #pragma unroll
        for (int mt = 0; mt < 4; ++mt) {
            #pragma unroll
            for (int nt = 0; nt < 4; ++nt)
                #pragma unroll
                for (int r = 0; r < 4; ++r)
                    sT[w][lq * 4 + r][nt * 16 + lr] =
                        fmaxf(acc[mt][nt][r] + bv[nt], 0.f);
            __syncthreads();
            const int r16 = mb + mt;
            #pragma unroll
            for (int gg = 0; gg < 2; ++gg) {
                ushort h0[8], h1v[8];
                #pragma unroll
                for (int jj = 0; jj < 8; ++jj) {
                    float v = sT[w][lr][gg * 32 + lq * 8 + jj];
                    split2(v, h0[jj], h1v[jj]);
                }
                const size_t off =
                    ((size_t)(r16 * KH32 + blockIdx.x * 2 + gg) * 64 + l) * 8;
                nt_store16(outP0 + off, *(const u32x4*)h0);
                nt_store16(outP1 + off, *(const u32x4*)h1v);
            }
            __syncthreads();
        }
    } else {
        float wv[4];
        #pragma unroll
        for (int nt = 0; nt < 4; ++nt) wv[nt] = W3[n0 + nt * 16 + lr];
        #pragma unroll
        for (int mt = 0; mt < 4; ++mt)
            #pragma unroll
            for (int r = 0; r < 4; ++r) {
                float v = 0.f;
                #pragma unroll
                for (int nt = 0; nt < 4; ++nt)
                    v += fmaxf(acc[mt][nt][r] + bv[nt], 0.f) * wv[nt];
                v += __shfl_xor(v, 1);
                v += __shfl_xor(v, 2);
                v += __shfl_xor(v, 4);
                v += __shfl_xor(v, 8);
                if (lr == 0)
                    outF[(size_t)blockIdx.x * M_ + (mb + mt) * 16 + lq * 4 + r] = v;
            }
    }
}

// ===========================================================================
// FALLBACK PATH (R2, ~147 MB ws) — unchanged, proven correct.
// ===========================================================================
__global__ void split_w_panel(const float* __restrict__ W, ushort* __restrict__ P0,
                              ushort* __restrict__ P1, ushort* __restrict__ P2, int K8)
{
    const int idx = blockIdx.x * 256 + threadIdx.x;
    if (idx >= K8 * 1024) return;
    const int k8 = idx >> 10;
    const int n  = idx & 1023;
    ushort h0[8], h1[8], h2[8];
    #pragma unroll
    for (int j = 0; j < 8; ++j) {
        float w = W[(size_t)(k8 * 8 + j) * 1024 + n];
        split1(w, h0[j], h1[j], h2[j]);
    }
    *(uint4*)(P0 + (size_t)idx * 8) = *(uint4*)h0;
    *(uint4*)(P1 + (size_t)idx * 8) = *(uint4*)h1;
    *(uint4*)(P2 + (size_t)idx * 8) = *(uint4*)h2;
}

template<int KDIM, bool FUSE>
__global__ __launch_bounds__(256, 2) void gemm_split(
    const float* __restrict__ A,
    const ushort* __restrict__ P0, const ushort* __restrict__ P1,
    const ushort* __restrict__ P2,
    const float* __restrict__ bias, const float* __restrict__ W3,
    float* __restrict__ out)
{
    __shared__ ushort aLds[3][4 * 257 * 8];
    __shared__ ushort bLds[3][4 * 65 * 8];

    const int tid   = threadIdx.x;
    const int lane  = tid & 63;
    const int lr    = lane & 15;
    const int lq    = lane >> 4;
    const int waveM = (tid >> 6) * 64;
    const int m0    = blockIdx.y * 256;
    const int n0    = blockIdx.x * 64;

    const int bq = tid >> 6;
    const int bn = tid & 63;
    const int ar = tid >> 3;
    const int ac4 = tid & 7;

    f32x4 acc[4][4] = {};

    for (int kt = 0; kt < KDIM / 32; ++kt) {
        const int k80 = kt * 4;
        const size_t bchunk = ((size_t)(k80 + bq) * 1024 + n0 + bn) * 8;
        uint4 bf0 = *(const uint4*)(P0 + bchunk);
        uint4 bf1 = *(const uint4*)(P1 + bchunk);
        uint4 bf2 = *(const uint4*)(P2 + bchunk);
        float4 av[8];
        #pragma unroll
        for (int sw = 0; sw < 8; ++sw) {
            const int row = sw * 32 + ar;
            av[sw] = *(const float4*)(A + (size_t)(m0 + row) * KDIM + kt * 32 + ac4 * 4);
        }
        __syncthreads();
        *(uint4*)&bLds[0][(bq * 65 + bn) * 8] = bf0;
        *(uint4*)&bLds[1][(bq * 65 + bn) * 8] = bf1;
        *(uint4*)&bLds[2][(bq * 65 + bn) * 8] = bf2;
        #pragma unroll
        for (int sw = 0; sw < 8; ++sw) {
            const int row = sw * 32 + ar;
            uint2 q0, q1, q2;
            split4(av[sw], q0, q1, q2);
            const int off = ((ac4 >> 1) * 257 + row) * 8 + (ac4 & 1) * 4;
            *(uint2*)&aLds[0][off] = q0;
            *(uint2*)&aLds[1][off] = q1;
            *(uint2*)&aLds[2][off] = q2;
        }
        __syncthreads();

        s16x8 B0[4], B1[4], B2[4];
        #pragma unroll
        for (int nt = 0; nt < 4; ++nt) {
            const int boff = (lq * 65 + nt * 16 + lr) * 8;
            B0[nt] = *(const s16x8*)&bLds[0][boff];
            B1[nt] = *(const s16x8*)&bLds[1][boff];
            B2[nt] = *(const s16x8*)&bLds[2][boff];
        }
        #pragma unroll
        for (int mt = 0; mt < 4; ++mt) {
            const int aoff = (lq * 257 + waveM + mt * 16 + lr) * 8;
            s16x8 A0 = *(const s16x8*)&aLds[0][aoff];
            s16x8 A1 = *(const s16x8*)&aLds[1][aoff];
            s16x8 A2 = *(const s16x8*)&aLds[2][aoff];
            #pragma unroll
            for (int nt = 0; nt < 4; ++nt) {
                f32x4 c = acc[mt][nt];
                c = mfma16(A0, B0[nt], c);
                c = mfma16(A0, B1[nt], c);
                c = mfma16(A1, B0[nt], c);
                c = mfma16(A1, B1[nt], c);
                c = mfma16(A0, B2[nt], c);
                c = mfma16(A2, B0[nt], c);
                acc[mt][nt] = c;
            }
        }
    }

    float bv[4];
    #pragma unroll
    for (int nt = 0; nt < 4; ++nt) bv[nt] = bias[n0 + nt * 16 + lr];

    if (!FUSE) {
        #pragma unroll
        for (int mt = 0; mt < 4; ++mt)
            #pragma unroll
            for (int nt = 0; nt < 4; ++nt)
                #pragma unroll
                for (int r = 0; r < 4; ++r) {
                    const int row = m0 + waveM + mt * 16 + lq * 4 + r;
                    out[(size_t)row * 1024 + n0 + nt * 16 + lr] =
                        fmaxf(acc[mt][nt][r] + bv[nt], 0.f);
                }
    } else {
        float wv[4];
        #pragma unroll
        for (int nt = 0; nt < 4; ++nt) wv[nt] = W3[n0 + nt * 16 + lr];
        #pragma unroll
        for (int mt = 0; mt < 4; ++mt)
            #pragma unroll
            for (int r = 0; r < 4; ++r) {
                float v = 0.f;
                #pragma unroll
                for (int nt = 0; nt < 4; ++nt)
                    v += fmaxf(acc[mt][nt][r] + bv[nt], 0.f) * wv[nt];
                v += __shfl_xor(v, 1);
                v += __shfl_xor(v, 2);
                v += __shfl_xor(v, 4);
                v += __shfl_xor(v, 8);
                if (lr == 0)
                    out[(size_t)blockIdx.x * M_ + m0 + waveM + mt * 16 + lq * 4 + r] = v;
            }
    }
}

// ===========================================================================
// Top-K / gather / masks (shared by both paths)
// ===========================================================================
__device__ __forceinline__ uint64_t score_key(float s, int idx) {
    unsigned u = __float_as_uint(s);
    u = (u & 0x80000000u) ? ~u : (u | 0x80000000u);
    return ((uint64_t)u << 32) | (uint64_t)(0xFFFFFFFFu - (unsigned)idx);
}

__device__ __forceinline__ float compute_score(
    const float* __restrict__ partial, const float* __restrict__ mask,
    float b3v, int b, int i)
{
    const int m = b * TL_ + i;
    float s = b3v;
    #pragma unroll
    for (int cb = 0; cb < NPART; ++cb) s += partial[(size_t)cb * M_ + m];
    s -= (1.0f - mask[m]) * 10000.0f;
    return s;
}

__global__ __launch_bounds__(1024) void topk_kernel(
    const float* __restrict__ partial, const float* __restrict__ span_mask,
    const int* __restrict__ span_begin, const int* __restrict__ span_end,
    const int* __restrict__ seq_len, const float* __restrict__ b3,
    float* __restrict__ out, int* __restrict__ topk_ws)
{
    __shared__ uint64_t keys[NSORT];
    const int tid = threadIdx.x;
    const int b   = blockIdx.x;
    const float b3v = b3[0];

    for (int i = tid; i < NSORT; i += 1024) {
        if (i < TL_) {
            float s = compute_score(partial, span_mask, b3v, b, i);
            out[OFF_PRUNE + b * TL_ + i] = s;
            keys[i] = score_key(s, i);
        } else {
            keys[i] = 0ull;
        }
    }
    __syncthreads();

    for (unsigned kk = 2; kk <= NSORT; kk <<= 1) {
        for (unsigned j = kk >> 1; j > 0; j >>= 1) {
            for (unsigned i = (unsigned)tid; i < NSORT; i += 1024) {
                unsigned ixj = i ^ j;
                if (ixj > i) {
                    uint64_t x = keys[i], y = keys[ixj];
                    bool desc = ((i & kk) == 0);
                    if (desc ? (x < y) : (x > y)) { keys[i] = y; keys[ixj] = x; }
                }
            }
            __syncthreads();
        }
    }

    const uint64_t cutoff = keys[K_SPANS - 1];
    __syncthreads();

    unsigned* sScan = (unsigned*)keys;
    unsigned base = 0;
    const unsigned lane = tid & 63;
    const unsigned wv   = tid >> 6;
    for (int c = 0; c < TL_; c += 1024) {
        const int i = c + tid;
        bool flag = false; float s = 0.f;
        if (i < TL_) {
            // Read back the score stored in pass 1 (bitwise identical).
            s = out[OFF_PRUNE + b * TL_ + i];
            flag = (score_key(s, i) >= cutoff);
        }
        uint64_t bal = __ballot(flag);
        unsigned pre = (unsigned)__popcll(bal & ((1ull << lane) - 1ull));
        if (lane == 0) sScan[wv] = (unsigned)__popcll(bal);
        __syncthreads();
        unsigned woff = 0, tot = 0;
        for (int w = 0; w < 16; ++w) {
            unsigned v = sScan[w];
            if (w < (int)wv) woff += v;
            tot += v;
        }
        if (flag) {
            const int g = b * K_SPANS + (int)(base + woff + pre);
            topk_ws[g]        = i;
            out[OFF_TOP + g]  = (float)i;
            out[OFF_FSC + g]  = s;
            out[OFF_FBEG + g] = (float)span_begin[b * TL_ + i];
            out[OFF_FEND + g] = (float)span_end[b * TL_ + i];
        }
        base += tot;
        __syncthreads();
    }

    if (tid == 0)
        out[OFF_SL + b] = ceilf(0.4f * (float)seq_len[b]);
}

__global__ void gather_vecs(const float* __restrict__ span_vecs,
                            const int* __restrict__ topk_ws,
                            float* __restrict__ out)
{
    const int bk  = blockIdx.x;
    const int b   = bk / K_SPANS;
    const int row = topk_ws[bk];
    const float4* src = (const float4*)(span_vecs + ((size_t)b * TL_ + row) * D_);
    float4* dst = (float4*)(out + OFF_FVECS + (size_t)bk * D_);
    for (int j = threadIdx.x; j < D_ / 4; j += blockDim.x) dst[j] = src[j];
}

__global__ void masks_kernel(const int* __restrict__ seq_len,
                             float* __restrict__ out)
{
    const int idx = blockIdx.x * blockDim.x + threadIdx.x;
    if (idx >= B_ * K_SPANS * K_SPANS) return;
    const int b = idx / (K_SPANS * K_SPANS);
    const int r = idx - b * K_SPANS * K_SPANS;
    const int i = r / K_SPANS;
    const int j = r - i * K_SPANS;
    const int sl = (int)ceilf(0.4f * (float)seq_len[b]);
    const float v = (i < sl && j < sl) ? 1.0f : 0.0f;
    out[OFF_SQ + idx]  = v;
    out[OFF_TRI + idx] = (j <= i) ? v : 0.0f;
}

// ===========================================================================
extern "C" void kernel_launch(void* const* d_in, const int* in_sizes, int n_in,
                              void* d_out, int out_size, void* d_ws, size_t ws_size,
                              hipStream_t stream)
{
    const float* span_vecs  = (const float*)d_in[0];
    const float* span_mask  = (const float*)d_in[1];
    const int*   span_begin = (const int*)  d_in[2];
    const int*   span_end   = (const int*)  d_in[3];
    const int*   seq_len    = (const int*)  d_in[4];
    const float* W1 = (const float*)d_in[5];
    const float* b1 = (const float*)d_in[6];
    const float* W2 = (const float*)d_in[7];
    const float* b2 = (const float*)d_in[8];
    const float* W3 = (const float*)d_in[9];
    const float* b3 = (const float*)d_in[10];
    float* out = (float*)d_out;

    const size_t A1CH = (size_t)M_ * D_;        // ushorts per A1 panel chunk
    const size_t H1CH = (size_t)M_ * H_;        // ushorts per h1 panel chunk
    const size_t W1CH = (size_t)D_ * H_;        // ushorts per W1 panel chunk
    const size_t W2CH = (size_t)H_ * H_;        // ushorts per W2 panel chunk
    const size_t FAST_NEED =
        2 * A1CH * 2 + 2 * H1CH * 2 +
        2 * W1CH * 2 + 2 * W2CH * 2 + (size_t)NPART * M_ * 4 + 4096;

    float* partial;
    int*   topk_ws;

    if (ws_size >= FAST_NEED) {
        // ---------------- fast path: LDS-free fragment-panel GEMMs ----------
        char* p = (char*)d_ws;
        ushort* a1p0 = (ushort*)p;  p += A1CH * 2;
        ushort* a1p1 = (ushort*)p;  p += A1CH * 2;
        ushort* h1p0 = (ushort*)p;  p += H1CH * 2;
        ushort* h1p1 = (ushort*)p;  p += H1CH * 2;
        ushort* w1p0 = (ushort*)p;  p += W1CH * 2;
        ushort* w1p1 = (ushort*)p;  p += W1CH * 2;
        ushort* w2p0 = (ushort*)p;  p += W2CH * 2;
        ushort* w2p1 = (ushort*)p;  p += W2CH * 2;
        partial      = (float*)p;   p += (size_t)NPART * M_ * 4;
        topk_ws      = (int*)p;

        split_a_panel<64><<<(M_ / 16) * 64 / 4, 256, 0, stream>>>(
            span_vecs, a1p0, a1p1);
        split_w_frag<64><<<(H_ / 16) * 64 * 64 / 256, 256, 0, stream>>>(
            W1, w1p0, w1p1);
        split_w_frag<32><<<(H_ / 16) * 32 * 64 / 256, 256, 0, stream>>>(
            W2, w2p0, w2p1);

        // GEMM1 writes h1 bf16 panels directly (fused relu+split epilogue).
        gemm_frag<64, false><<<dim3(16, M_ / 256), 256, 0, stream>>>(
            a1p0, a1p1, w1p0, w1p1, b1, nullptr, nullptr, h1p0, h1p1);
        gemm_frag<32, true><<<dim3(16, M_ / 256), 256, 0, stream>>>(
            h1p0, h1p1, w2p0, w2p1, b2, W3, partial, nullptr, nullptr);
    } else {
        // ---------------- fallback: R2 path (proven, ~147 MB) ---------------
        float*  h1   = (float*)d_ws;
        partial      = h1 + (size_t)M_ * H_;
        ushort* w1p0 = (ushort*)(partial + (size_t)NPART * M_);
        ushort* w1p1 = w1p0 + (size_t)256 * 1024 * 8;
        ushort* w1p2 = w1p1 + (size_t)256 * 1024 * 8;
        ushort* w2p0 = w1p2 + (size_t)256 * 1024 * 8;
        ushort* w2p1 = w2p0 + (size_t)128 * 1024 * 8;
        ushort* w2p2 = w2p1 + (size_t)128 * 1024 * 8;
        topk_ws      = (int*)(w2p2 + (size_t)128 * 1024 * 8);

        split_w_panel<<<(256 * 1024) / 256, 256, 0, stream>>>(W1, w1p0, w1p1, w1p2, 256);
        split_w_panel<<<(128 * 1024) / 256, 256, 0, stream>>>(W2, w2p0, w2p1, w2p2, 128);
        gemm_split<2048, false><<<dim3(16, 120), 256, 0, stream>>>(
            span_vecs, w1p0, w1p1, w1p2, b1, nullptr, h1);
        gemm_split<1024, true><<<dim3(16, 120), 256, 0, stream>>>(
            h1, w2p0, w2p1, w2p2, b2, W3, partial);
    }

    topk_kernel<<<B_, 1024, 0, stream>>>(
        partial, span_mask, span_begin, span_end, seq_len, b3, out, topk_ws);
    gather_vecs<<<B_ * K_SPANS, 256, 0, stream>>>(span_vecs, topk_ws, out);
    masks_kernel<<<(B_ * K_SPANS * K_SPANS + 255) / 256, 256, 0, stream>>>(
        seq_len, out);
}